// Round 4
// baseline (3997.588 us; speedup 1.0000x reference)
//
#include <hip/hip_runtime.h>

// Clipped shallow PLRNN: z_{t+1} = A*z_t + (relu(z@W2 + h2) - relu(z@W2)) @ W1 + h1
// x[b][t][:] = z_t @ OB + Ob,  t = 0..nt
//
// n_states=64, n_hidden=256, bs=256, nt=4096.
// Batch rows are independent -> 1 row per workgroup, 256 WGs == 256 CUs.
// All weights live in VGPRs; z (64 f32) and phi (256 f32, padded) in LDS.

#define NS 64
#define NH 256
#define BS 256

__global__ __launch_bounds__(256, 1)
void plrnn_kernel(const float* __restrict__ z0,
                  const float* __restrict__ A,
                  const float* __restrict__ W1,   // [NH][NS]
                  const float* __restrict__ W2,   // [NS][NH]
                  const float* __restrict__ h1,
                  const float* __restrict__ h2,
                  const float* __restrict__ OB,   // [NS][NS]
                  const float* __restrict__ Ob,
                  const int* __restrict__ ntp,
                  float* __restrict__ X)          // [BS][nt+1][NS]
{
    const int b   = blockIdx.x;
    const int tid = threadIdx.x;
    const int o   = tid >> 2;   // output index (phase2 / obs), 0..63
    const int s   = tid & 3;    // reduction slice, 0..3
    const int nt  = *ntp;

    __shared__ float zs[NS];
    __shared__ float phiL[4 * 68];  // phi slice s at offset s*68 (pad 4 floats -> conflict-free f4 reads)

    // ---- stage weights into registers (static indices only -> VGPRs) ----
    float w2c[64];                  // W2[:, tid]
    #pragma unroll
    for (int i = 0; i < 64; ++i) w2c[i] = W2[i * NH + tid];
    float w1c[64];                  // W1[s*64 + m, o]
    #pragma unroll
    for (int m = 0; m < 64; ++m) w1c[m] = W1[((s << 6) + m) * NS + o];
    float obc[16];                  // OB[s*16 + i, o]
    #pragma unroll
    for (int i = 0; i < 16; ++i) obc[i] = OB[((s << 4) + i) * NS + o];

    const float hA  = A[o];
    const float hh1 = h1[o];
    const float hh2 = h2[tid];
    const float hOb = Ob[o];

    if (tid < NS) zs[tid] = z0[b * NS + tid];
    __syncthreads();

    float* __restrict__ Xb = X + (size_t)b * (size_t)(nt + 1) * NS;

    const float4* zs4 = reinterpret_cast<const float4*>(zs);
    const float4* ph4 = reinterpret_cast<const float4*>(phiL + s * 68);

    for (int t = 0; ; ++t) {
        // ---- all zs reads for this step (phase1 dot, obs dot, zold) ----
        float a0 = 0.f, a1 = 0.f, a2 = 0.f, a3 = 0.f;
        #pragma unroll
        for (int i4 = 0; i4 < 16; ++i4) {
            float4 z4 = zs4[i4];                  // broadcast read
            a0 = fmaf(z4.x, w2c[4 * i4 + 0], a0);
            a1 = fmaf(z4.y, w2c[4 * i4 + 1], a1);
            a2 = fmaf(z4.z, w2c[4 * i4 + 2], a2);
            a3 = fmaf(z4.w, w2c[4 * i4 + 3], a3);
        }
        float x0 = 0.f, x1 = 0.f, x2 = 0.f, x3 = 0.f;
        #pragma unroll
        for (int i4 = 0; i4 < 4; ++i4) {
            float4 z4 = zs4[4 * s + i4];
            x0 = fmaf(z4.x, obc[4 * i4 + 0], x0);
            x1 = fmaf(z4.y, obc[4 * i4 + 1], x1);
            x2 = fmaf(z4.z, obc[4 * i4 + 2], x2);
            x3 = fmaf(z4.w, obc[4 * i4 + 3], x3);
        }
        float zold = zs[o];

        // ---- observation x_t = z_t @ OB + Ob ----
        float xr = (x0 + x1) + (x2 + x3);
        xr += __shfl_xor(xr, 1);
        xr += __shfl_xor(xr, 2);
        if (s == 0) Xb[(size_t)t * NS + o] = xr + hOb;

        if (t == nt) break;

        // ---- nonlinearity + phi exchange ----
        float W2z = (a0 + a1) + (a2 + a3);
        float ph  = fmaxf(W2z + hh2, 0.f) - fmaxf(W2z, 0.f);
        phiL[(tid >> 6) * 68 + (tid & 63)] = ph;   // stride-1 per wave, conflict-free
        __syncthreads();                           // phi visible; all zs reads done

        // ---- phase 2: p = phi @ W1 (slice s), reduce over 4 lanes ----
        float p0 = 0.f, p1 = 0.f, p2 = 0.f, p3 = 0.f;
        #pragma unroll
        for (int m4 = 0; m4 < 16; ++m4) {
            float4 f = ph4[m4];                    // padded -> conflict-free
            p0 = fmaf(f.x, w1c[4 * m4 + 0], p0);
            p1 = fmaf(f.y, w1c[4 * m4 + 1], p1);
            p2 = fmaf(f.z, w1c[4 * m4 + 2], p2);
            p3 = fmaf(f.w, w1c[4 * m4 + 3], p3);
        }
        float p = (p0 + p1) + (p2 + p3);
        p += __shfl_xor(p, 1);
        p += __shfl_xor(p, 2);

        if (s == 0) zs[o] = fmaf(hA, zold, p + hh1);
        __syncthreads();                           // z_{t+1} visible
    }
}

extern "C" void kernel_launch(void* const* d_in, const int* in_sizes, int n_in,
                              void* d_out, int out_size, void* d_ws, size_t ws_size,
                              hipStream_t stream) {
    const float* z0 = (const float*)d_in[0];
    const float* A  = (const float*)d_in[1];
    const float* W1 = (const float*)d_in[2];
    const float* W2 = (const float*)d_in[3];
    const float* h1 = (const float*)d_in[4];
    const float* h2 = (const float*)d_in[5];
    const float* OB = (const float*)d_in[6];
    const float* Ob = (const float*)d_in[7];
    const int*   ntp = (const int*)d_in[8];
    float* X = (float*)d_out;

    plrnn_kernel<<<BS, 256, 0, stream>>>(z0, A, W1, W2, h1, h2, OB, Ob, ntp, X);
}

// Round 5
// 2704.408 us; speedup vs baseline: 1.4782x; 1.4782x over previous
//
#include <hip/hip_runtime.h>

// Clipped shallow PLRNN, LDS-traffic-minimized version.
// z_{t+1} = A*z_t + (relu(z@W2+h2) - relu(z@W2)) @ W1 + h1 ; x_t = z_t@OB + Ob
// n_states=64, n_hidden=256, bs=256, nt=4096. One row per CU (256 WGs x 256 thr).
//
// Thread (g = tid>>2, s = tid&3), wave w = tid>>6:
//  phase1: thread reads z-slice s (16 floats, 4x b128), partials for hidden
//          outputs {4g..4g+3}, DPP quad reduce-scatter -> W2z[tid] on thread tid.
//  obs:    reuses the same z-slice regs (0 extra LDS), quad full-reduce.
//  phase2: reads phi slice s (64 floats, 16x b128, pad-68 conflict-free),
//          quad full-reduce -> p[g] on all 4 lanes; zcur kept in register.
// LDS instrs/CU/step: ~88 vs ~152 in round-0 kernel.

#define NS 64
#define NH 256
#define BS 256

__device__ __forceinline__ float dppx1(float x) {  // quad_perm [1,0,3,2] == xor 1
    return __int_as_float(__builtin_amdgcn_mov_dpp(__float_as_int(x), 0xB1, 0xF, 0xF, true));
}
__device__ __forceinline__ float dppx2(float x) {  // quad_perm [2,3,0,1] == xor 2
    return __int_as_float(__builtin_amdgcn_mov_dpp(__float_as_int(x), 0x4E, 0xF, 0xF, true));
}

__global__ __launch_bounds__(256, 1)
void plrnn_kernel(const float* __restrict__ z0,
                  const float* __restrict__ A,
                  const float* __restrict__ W1,   // [NH][NS]
                  const float* __restrict__ W2,   // [NS][NH]
                  const float* __restrict__ h1,
                  const float* __restrict__ h2,
                  const float* __restrict__ OB,   // [NS][NS]
                  const float* __restrict__ Ob,
                  const int* __restrict__ ntp,
                  float* __restrict__ X)          // [BS][nt+1][NS]
{
    const int b   = blockIdx.x;
    const int tid = threadIdx.x;
    const int g   = tid >> 2;     // output index for obs/phase2, 0..63
    const int s   = tid & 3;      // slice index, 0..3
    const int w   = tid >> 6;     // wave, 0..3
    const int nt  = *ntp;
    const bool s1  = (s & 1) != 0;
    const bool s2b = (s & 2) != 0;

    __shared__ __align__(16) float zsh[NS];
    __shared__ __align__(16) float phish[4 * 68];   // slice s at offset 68*s (conflict-free f4)

    // ---- weights in registers (whole block covers each matrix exactly once) ----
    float4 w2r[16];                 // w2r[k] = W2[16s+k][4g..4g+3]
    #pragma unroll
    for (int k = 0; k < 16; ++k)
        w2r[k] = *reinterpret_cast<const float4*>(&W2[(16 * s + k) * NH + 4 * g]);
    float w1r[64];                  // w1r[m] = W1[64s+m][g]
    #pragma unroll
    for (int m = 0; m < 64; ++m) w1r[m] = W1[(64 * s + m) * NS + g];
    float obr[16];                  // obr[k] = OB[16s+k][g]
    #pragma unroll
    for (int k = 0; k < 16; ++k) obr[k] = OB[(16 * s + k) * NS + g];

    const float hA  = A[g];
    const float hh1 = h1[g];
    const float hh2 = h2[tid];      // phi for hidden unit `tid`
    const float hOb = Ob[g];
    float zcur = z0[b * NS + g];    // z[g] lives in a register on all 4 quad lanes

    if (tid < NS) zsh[tid] = z0[b * NS + tid];
    __syncthreads();

    float* __restrict__ Xb = X + (size_t)b * (size_t)(nt + 1) * NS;
    const float4* zs4 = reinterpret_cast<const float4*>(zsh) + 4 * s;     // slice s
    const float4* ph4 = reinterpret_cast<const float4*>(phish + 68 * s);  // slice s

    for (int t = 0; t < nt; ++t) {
        // ---- read z-slice s (4x b128, 2-way bank alias = free) ----
        float4 za = zs4[0], zb = zs4[1], zc = zs4[2], zd = zs4[3];
        const float zz[16] = {za.x, za.y, za.z, za.w, zb.x, zb.y, zb.z, zb.w,
                              zc.x, zc.y, zc.z, zc.w, zd.x, zd.y, zd.z, zd.w};

        // ---- phase1 partials: 4 hidden outputs {4g+j} over slice s ----
        float q0 = 0.f, q1 = 0.f, q2 = 0.f, q3 = 0.f;
        #pragma unroll
        for (int k = 0; k < 16; ++k) {
            q0 = fmaf(zz[k], w2r[k].x, q0);
            q1 = fmaf(zz[k], w2r[k].y, q1);
            q2 = fmaf(zz[k], w2r[k].z, q2);
            q3 = fmaf(zz[k], w2r[k].w, q3);
        }
        // ---- obs partial (reuses zz; output g over slice s) ----
        float xo = 0.f;
        #pragma unroll
        for (int k = 0; k < 16; ++k) xo = fmaf(zz[k], obr[k], xo);

        // ---- quad reduce-scatter: thread tid ends with W2z[tid] ----
        float sA = s1 ? q0 : q1;  float rA = dppx1(sA);  float k0 = (s1 ? q1 : q0) + rA;
        float sB = s1 ? q2 : q3;  float rB = dppx1(sB);  float k1 = (s1 ? q3 : q2) + rB;
        float sC = s2b ? k0 : k1; float rC = dppx2(sC);  float W2z = (s2b ? k1 : k0) + rC;

        float ph = fmaxf(W2z + hh2, 0.f) - fmaxf(W2z, 0.f);
        phish[w * 68 + (tid & 63)] = ph;

        // ---- obs full-reduce + store ----
        float xr = xo;
        xr += dppx1(xr);
        xr += dppx2(xr);
        if (s == 0) Xb[(size_t)t * NS + g] = xr + hOb;

        __syncthreads();   // phi visible; zsh reads done before rewrite

        // ---- phase2: p[g] partial over phi slice s (16x b128, conflict-free) ----
        float p0 = 0.f, p1 = 0.f, p2 = 0.f, p3 = 0.f;
        #pragma unroll
        for (int i = 0; i < 16; ++i) {
            float4 f = ph4[i];
            p0 = fmaf(f.x, w1r[4 * i + 0], p0);
            p1 = fmaf(f.y, w1r[4 * i + 1], p1);
            p2 = fmaf(f.z, w1r[4 * i + 2], p2);
            p3 = fmaf(f.w, w1r[4 * i + 3], p3);
        }
        float p = (p0 + p1) + (p2 + p3);
        p += dppx1(p);
        p += dppx2(p);

        zcur = fmaf(hA, zcur, p + hh1);     // all 4 quad lanes identical
        if (s == 0) zsh[g] = zcur;          // 1 predicated write/wave

        __syncthreads();   // z_{t+1} visible; phish reads done before rewrite
    }

    // ---- final observation x_nt ----
    {
        float4 za = zs4[0], zb = zs4[1], zc = zs4[2], zd = zs4[3];
        const float zz[16] = {za.x, za.y, za.z, za.w, zb.x, zb.y, zb.z, zb.w,
                              zc.x, zc.y, zc.z, zc.w, zd.x, zd.y, zd.z, zd.w};
        float xo = 0.f;
        #pragma unroll
        for (int k = 0; k < 16; ++k) xo = fmaf(zz[k], obr[k], xo);
        xo += dppx1(xo);
        xo += dppx2(xo);
        if (s == 0) Xb[(size_t)nt * NS + g] = xo + hOb;
    }
}

extern "C" void kernel_launch(void* const* d_in, const int* in_sizes, int n_in,
                              void* d_out, int out_size, void* d_ws, size_t ws_size,
                              hipStream_t stream) {
    const float* z0 = (const float*)d_in[0];
    const float* A  = (const float*)d_in[1];
    const float* W1 = (const float*)d_in[2];
    const float* W2 = (const float*)d_in[3];
    const float* h1 = (const float*)d_in[4];
    const float* h2 = (const float*)d_in[5];
    const float* OB = (const float*)d_in[6];
    const float* Ob = (const float*)d_in[7];
    const int*   ntp = (const int*)d_in[8];
    float* X = (float*)d_out;

    plrnn_kernel<<<BS, 256, 0, stream>>>(z0, A, W1, W2, h1, h2, OB, Ob, ntp, X);
}

// Round 7
// 2102.631 us; speedup vs baseline: 1.9012x; 1.2862x over previous
//
#include <hip/hip_runtime.h>

// Clipped shallow PLRNN — packed-FMA + minimal-LDS version.
// z_{t+1} = A*z_t + (relu(z@W2+h2) - relu(z@W2)) @ W1 + h1 ; x_t = z_t@OB + Ob
// n_states=64, n_hidden=256, bs=256, nt=4096. One row per CU (256 WGs x 256 thr).
//
// Phase1 (z@W2): thread (g=tid>>2, s=tid&3) reads z slice s (4x b128),
//   4 packed partials -> quad reduce-scatter -> W2z[tid] -> phi -> LDS write.
// Obs: reuses z-slice regs, packed dot + quad full-reduce.
// Phase2 (phi@W1): thread reads phi[16S..16S+15] (4x b128), S=(b5,b3,b1,b0),
//   4 packed partials for outputs 16w+4*(b4,b2)+j; scatter over b0 (quad xor1),
//   b1 (quad xor2); full-reduce over b3 (row_ror:8) and b5 (shfl_xor 32).
//   z kept in registers under this mapping; 1 predicated zsh write per lane-group.
// LDS-unit instrs/CU/step ~41 (was ~88); VALU FMAs packed 2x (v_pk_fma_f32).

#define NS 64
#define NH 256
#define BS 256

typedef float v2f __attribute__((ext_vector_type(2)));

__device__ __forceinline__ float dppx1(float x) {  // quad_perm [1,0,3,2] == xor 1
    return __int_as_float(__builtin_amdgcn_mov_dpp(__float_as_int(x), 0xB1, 0xF, 0xF, true));
}
__device__ __forceinline__ float dppx2(float x) {  // quad_perm [2,3,0,1] == xor 2
    return __int_as_float(__builtin_amdgcn_mov_dpp(__float_as_int(x), 0x4E, 0xF, 0xF, true));
}
__device__ __forceinline__ float dppror8(float x) { // row_ror:8 == xor 8 within 16-lane row
    return __int_as_float(__builtin_amdgcn_mov_dpp(__float_as_int(x), 0x128, 0xF, 0xF, true));
}

__global__ __launch_bounds__(256, 1)
void plrnn_kernel(const float* __restrict__ z0,
                  const float* __restrict__ A,
                  const float* __restrict__ W1,   // [NH][NS]
                  const float* __restrict__ W2,   // [NS][NH]
                  const float* __restrict__ h1,
                  const float* __restrict__ h2,
                  const float* __restrict__ OB,   // [NS][NS]
                  const float* __restrict__ Ob,
                  const int* __restrict__ ntp,
                  float* __restrict__ X)          // [BS][nt+1][NS]
{
    const int b    = blockIdx.x;
    const int tid  = threadIdx.x;
    const int g    = tid >> 2;    // phase1/obs output index
    const int s    = tid & 3;     // phase1/obs slice
    const int w    = tid >> 6;    // wave
    const int lane = tid & 63;
    const int nt   = *ntp;
    const bool s1  = (s & 1) != 0;
    const bool s2b = (s & 2) != 0;

    // phase2 lane decomposition
    const int b0 = lane & 1, b1 = (lane >> 1) & 1, b2 = (lane >> 2) & 1;
    const int b4 = (lane >> 4) & 1;
    const bool bb0 = b0 != 0, bb1 = b1 != 0;
    const int S2 = b0 | (b1 << 1) | (((lane >> 3) & 1) << 2) | (((lane >> 5) & 1) << 3);
    const int obase  = 16 * w + 4 * (b2 | (b4 << 1));  // 4 outputs obase..obase+3
    const int o_lane = obase + 2 * b1 + b0;            // this lane's final output

    __shared__ __align__(16) float zsh[NS];
    __shared__ __align__(16) float phish[4 * 68];      // producing wave w' at 68*w'

    // ---- weights in registers, packed in pairs along the reduction dim ----
    v2f w2p[4][8];   // w2p[j][k2] = {W2[16s+2k2][4g+j], W2[16s+2k2+1][4g+j]}
    #pragma unroll
    for (int k2 = 0; k2 < 8; ++k2) {
        const int r0 = 16 * s + 2 * k2;
        const float4 a0 = *reinterpret_cast<const float4*>(&W2[(r0 + 0) * NH + 4 * g]);
        const float4 a1 = *reinterpret_cast<const float4*>(&W2[(r0 + 1) * NH + 4 * g]);
        w2p[0][k2] = (v2f){a0.x, a1.x};
        w2p[1][k2] = (v2f){a0.y, a1.y};
        w2p[2][k2] = (v2f){a0.z, a1.z};
        w2p[3][k2] = (v2f){a0.w, a1.w};
    }
    v2f w1p[4][8];   // w1p[j][t2] = {W1[16*S2+2t2][obase+j], W1[16*S2+2t2+1][obase+j]}
    #pragma unroll
    for (int t2 = 0; t2 < 8; ++t2) {
        const int r0 = 16 * S2 + 2 * t2;
        const float4 a0 = *reinterpret_cast<const float4*>(&W1[(r0 + 0) * NS + obase]);
        const float4 a1 = *reinterpret_cast<const float4*>(&W1[(r0 + 1) * NS + obase]);
        w1p[0][t2] = (v2f){a0.x, a1.x};
        w1p[1][t2] = (v2f){a0.y, a1.y};
        w1p[2][t2] = (v2f){a0.z, a1.z};
        w1p[3][t2] = (v2f){a0.w, a1.w};
    }
    v2f obp[8];      // obp[k2] = {OB[16s+2k2][g], OB[16s+2k2+1][g]}
    #pragma unroll
    for (int k2 = 0; k2 < 8; ++k2)
        obp[k2] = (v2f){OB[(16 * s + 2 * k2) * NS + g], OB[(16 * s + 2 * k2 + 1) * NS + g]};

    const float hA  = A[o_lane];
    const float hh1 = h1[o_lane];
    const float hh2 = h2[tid];
    const float hOb = Ob[g];
    float zcur = z0[b * NS + o_lane];   // z[o_lane], 4 copies across (b3,b5)

    if (tid < NS) zsh[tid] = z0[b * NS + tid];
    __syncthreads();

    float* __restrict__ Xb = X + (size_t)b * (size_t)(nt + 1) * NS;
    const float4* zs4  = reinterpret_cast<const float4*>(zsh) + 4 * s;
    const float4* ph4b = reinterpret_cast<const float4*>(phish + 68 * (S2 >> 2) + 16 * (S2 & 3));

    for (int t = 0; t < nt; ++t) {
        // ---- z slice s -> registers (4x b128, broadcast, <=2-way alias) ----
        const float4 za = zs4[0], zb = zs4[1], zc = zs4[2], zd = zs4[3];
        const v2f zz2[8] = {{za.x, za.y}, {za.z, za.w}, {zb.x, zb.y}, {zb.z, zb.w},
                            {zc.x, zc.y}, {zc.z, zc.w}, {zd.x, zd.y}, {zd.z, zd.w}};

        // ---- phase1 packed partials: hidden outputs 4g..4g+3 over slice s ----
        v2f q0 = {0.f, 0.f}, q1 = {0.f, 0.f}, q2 = {0.f, 0.f}, q3 = {0.f, 0.f};
        #pragma unroll
        for (int k2 = 0; k2 < 8; ++k2) {
            q0 = __builtin_elementwise_fma(zz2[k2], w2p[0][k2], q0);
            q1 = __builtin_elementwise_fma(zz2[k2], w2p[1][k2], q1);
            q2 = __builtin_elementwise_fma(zz2[k2], w2p[2][k2], q2);
            q3 = __builtin_elementwise_fma(zz2[k2], w2p[3][k2], q3);
        }
        const float p0 = q0.x + q0.y, p1 = q1.x + q1.y, p2 = q2.x + q2.y, p3 = q3.x + q3.y;

        // ---- obs packed partial (reuses zz2) ----
        v2f xop = {0.f, 0.f};
        #pragma unroll
        for (int k2 = 0; k2 < 8; ++k2) xop = __builtin_elementwise_fma(zz2[k2], obp[k2], xop);

        // ---- phase1 quad reduce-scatter -> W2z[tid] ----
        float sA = s1 ? p0 : p1;  float rA = dppx1(sA);  float k0 = (s1 ? p1 : p0) + rA;
        float sB = s1 ? p2 : p3;  float rB = dppx1(sB);  float k1 = (s1 ? p3 : p2) + rB;
        float sC = s2b ? k0 : k1; float rC = dppx2(sC);  float W2z = (s2b ? k1 : k0) + rC;

        const float ph = fmaxf(W2z + hh2, 0.f) - fmaxf(W2z, 0.f);
        phish[w * 68 + lane] = ph;

        // ---- obs full quad reduce + store ----
        float xr = xop.x + xop.y;
        xr += dppx1(xr);
        xr += dppx2(xr);
        if (s == 0) Xb[(size_t)t * NS + g] = xr + hOb;

        __syncthreads();   // phi visible; zsh reads of step t complete

        // ---- phase2: 16 phi values (4x b128), 4 packed output-partials ----
        const float4 f0 = ph4b[0], f1 = ph4b[1], f2 = ph4b[2], f3 = ph4b[3];
        const v2f ff[8] = {{f0.x, f0.y}, {f0.z, f0.w}, {f1.x, f1.y}, {f1.z, f1.w},
                           {f2.x, f2.y}, {f2.z, f2.w}, {f3.x, f3.y}, {f3.z, f3.w}};
        v2f u0 = {0.f, 0.f}, u1 = {0.f, 0.f}, u2 = {0.f, 0.f}, u3 = {0.f, 0.f};
        #pragma unroll
        for (int t2 = 0; t2 < 8; ++t2) {
            u0 = __builtin_elementwise_fma(ff[t2], w1p[0][t2], u0);
            u1 = __builtin_elementwise_fma(ff[t2], w1p[1][t2], u1);
            u2 = __builtin_elementwise_fma(ff[t2], w1p[2][t2], u2);
            u3 = __builtin_elementwise_fma(ff[t2], w1p[3][t2], u3);
        }
        const float v0 = u0.x + u0.y, v1 = u1.x + u1.y, v2 = u2.x + u2.y, v3 = u3.x + u3.y;

        // scatter over b0 (xor1), b1 (xor2); reduce over b3 (ror8), b5 (shfl 32)
        float tA = bb0 ? v0 : v1;  float wA = dppx1(tA);  float kA = (bb0 ? v1 : v0) + wA;
        float tB = bb0 ? v2 : v3;  float wB = dppx1(tB);  float kB = (bb0 ? v3 : v2) + wB;
        float tC = bb1 ? kA : kB;  float wC = dppx2(tC);  float P  = (bb1 ? kB : kA) + wC;
        P += dppror8(P);
        P += __shfl_xor(P, 32);

        zcur = fmaf(hA, zcur, P + hh1);              // identical on all 4 (b3,b5) copies
        if ((lane & 40) == 0) zsh[o_lane] = zcur;    // 16 lanes/wave, distinct banks

        __syncthreads();   // z_{t+1} visible; phish reads of step t complete
    }

    // ---- final observation x_nt ----
    {
        const float4 za = zs4[0], zb = zs4[1], zc = zs4[2], zd = zs4[3];
        const v2f zz2[8] = {{za.x, za.y}, {za.z, za.w}, {zb.x, zb.y}, {zb.z, zb.w},
                            {zc.x, zc.y}, {zc.z, zc.w}, {zd.x, zd.y}, {zd.z, zd.w}};
        v2f xop = {0.f, 0.f};
        #pragma unroll
        for (int k2 = 0; k2 < 8; ++k2) xop = __builtin_elementwise_fma(zz2[k2], obp[k2], xop);
        float xr = xop.x + xop.y;
        xr += dppx1(xr);
        xr += dppx2(xr);
        if (s == 0) Xb[(size_t)nt * NS + g] = xr + hOb;
    }
}

extern "C" void kernel_launch(void* const* d_in, const int* in_sizes, int n_in,
                              void* d_out, int out_size, void* d_ws, size_t ws_size,
                              hipStream_t stream) {
    const float* z0 = (const float*)d_in[0];
    const float* A  = (const float*)d_in[1];
    const float* W1 = (const float*)d_in[2];
    const float* W2 = (const float*)d_in[3];
    const float* h1 = (const float*)d_in[4];
    const float* h2 = (const float*)d_in[5];
    const float* OB = (const float*)d_in[6];
    const float* Ob = (const float*)d_in[7];
    const int*   ntp = (const int*)d_in[8];
    float* X = (float*)d_out;

    plrnn_kernel<<<BS, 256, 0, stream>>>(z0, A, W1, W2, h1, h2, OB, Ob, ntp, X);
}